// Round 6
// baseline (503.395 us; speedup 1.0000x reference)
//
#include <hip/hip_runtime.h>

// GRU4Rec fused, round 11: RESUBMIT of round 10 (bench infra failed twice;
// no signal obtained — kernel unchanged).
//
// Change under test vs the 345us baseline: coalesced P16 layout.
// r9 post-mortem: proj TPW 5->1 REGRESSED (proj ~89 -> ~111 us): proj is
// store-bound, not TLP-bound. Old P layout [v][g] made each wave's store
// a 16-row x 32B scatter at 384B stride (38.4 MB of <=32B granules).
// New layout: P16 = [tile=v>>4][tt=12][p=4][m=16][q=4] halves. Proj store
// byte addr for lane l=m+16p at fixed tt is base + 8*l -> perfectly
// coalesced 512B per store instr. Scan prefetch: same 12 x 8B loads per
// lane at base(tile,m)+tt*512B (L2/L3-hit, 1-step prefetch slack).
// Scan source is otherwise byte-identical to the PROVEN Round-1 kernel
// (256 us, absmax 1.2e-4). One variable: the P16 index map (exact
// inverses on both sides).
//
// 4-wave scan split remains quarantined (r7/r8: identical 4.97e-2
// failures across different numerics => output never written; cause
// unlocalized). Scan attack resumes next round with proj banked.
//
// Shapes: B=4096, T=200, H=64, V=100000. Output fp32.

#define T_SEQ 200
#define HD 64
#define VOCAB 100000
#define PTILE 3072  // halves per vocab tile: [tt=12][p=4][m=16][q=4]
#define TPW 5       // 16-row vocab tiles per proj wave (1250 blocks)

typedef float v4f __attribute__((ext_vector_type(4)));
typedef float v8f __attribute__((ext_vector_type(8)));
typedef _Float16 v8h __attribute__((ext_vector_type(8)));
typedef _Float16 v4h __attribute__((ext_vector_type(4)));
typedef _Float16 h2 __attribute__((ext_vector_type(2)));
typedef unsigned v2u __attribute__((ext_vector_type(2)));

__device__ __forceinline__ float fsigmoid(float x) {
  float e = __builtin_amdgcn_exp2f(x * -1.442695040888963f);
  return __builtin_amdgcn_rcpf(1.0f + e);
}
__device__ __forceinline__ float ftanh(float x) {
  float e = __builtin_amdgcn_exp2f(x * -2.885390081777927f);
  return fmaf(2.0f, __builtin_amdgcn_rcpf(1.0f + e), -1.0f);
}
__device__ __forceinline__ float hlo(unsigned u) {
  h2 h = __builtin_bit_cast(h2, u);
  return (float)h[0];
}
__device__ __forceinline__ float hhi(unsigned u) {
  h2 h = __builtin_bit_cast(h2, u);
  return (float)h[1];
}
__device__ __forceinline__ unsigned pack_rne(float a, float b) {
  h2 w;
  w[0] = (_Float16)a;
  w[1] = (_Float16)b;
  return __builtin_bit_cast(unsigned, w);
}

// A-fragment of one [16 x 64] f32 row-major weight block (tile tau of 12,
// K-slice kappa of 2) for v_mfma_f32_16x16x32_f16.
// Lane l holds W[16*tau + (l&15)][32*kappa + 8*(l>>4) + j], j=0..7. RNE cvt.
__device__ __forceinline__ v8h load_wfrag(const float* __restrict__ W,
                                          int tau, int kappa, int m, int p) {
  const float* src = W + (size_t)(tau * 16 + m) * HD + kappa * 32 + p * 8;
  v8f f = *reinterpret_cast<const v8f*>(src);
  return __builtin_convertvector(f, v8h);
}

// ------------------------------------------------ phase 1: P = emb @ W_ih^T
// D[g][v] per gate-tile tt: lane (m,p) holds gates g=16tt+4p+q of vocab
// row tile*16+m. Store slot [tile][tt][p][m][q] -> byte addr base + 8*lane
// at fixed tt: fully coalesced 512B store per instruction.
__global__ __launch_bounds__(64) void gru_proj_mfma(
    const float* __restrict__ emb, const float* __restrict__ W_ih,
    _Float16* __restrict__ P16) {
  const int l = threadIdx.x;
  const int m = l & 15;
  const int p = l >> 4;

  v8h A[12][2];
#pragma unroll
  for (int tt = 0; tt < 12; ++tt) {
    A[tt][0] = load_wfrag(W_ih, tt, 0, m, p);
    A[tt][1] = load_wfrag(W_ih, tt, 1, m, p);
  }
  const v4f zz = {0.f, 0.f, 0.f, 0.f};

#pragma unroll 1
  for (int it = 0; it < TPW; ++it) {
    const int tile = blockIdx.x * TPW + it;
    if (tile * 16 >= VOCAB) break;
    const int v = tile * 16 + m;
    const float* erow = emb + (size_t)v * HD + p * 8;
    v8h B0 = __builtin_convertvector(*reinterpret_cast<const v8f*>(erow), v8h);
    v8h B1 = __builtin_convertvector(*reinterpret_cast<const v8f*>(erow + 32), v8h);
    _Float16* obase = P16 + (size_t)tile * PTILE + p * 64 + m * 4;
#pragma unroll
    for (int tt = 0; tt < 12; ++tt) {
      v4f acc = __builtin_amdgcn_mfma_f32_16x16x32_f16(A[tt][0], B0, zz, 0, 0, 0);
      acc = __builtin_amdgcn_mfma_f32_16x16x32_f16(A[tt][1], B1, acc, 0, 0, 0);
      *reinterpret_cast<v4h*>(obase + tt * 256) = __builtin_convertvector(acc, v4h);
    }
  }
}

// ------------------------------------------------ phase 2: recurrent scan
// One wave = 16 sequences (MFMA columns). Lane owns seq s = lane&15.
// Per step: prefetch gi(t+1) + tok(t+2); 24 MFMA -> gh; in-lane gates;
// fp32 h update; pack f16; freeze (t < L) into hpk; LDS transpose -> B frag.
// (Byte-identical to the proven Round-1 scan except P16 addressing.)

#define STEP(GC, GN)                                                          \
  {                                                                           \
    int i2_ = (t + 2 < L) ? (t + 2) : 0;                                      \
    int tk2_ = tokp[i2_];                                                     \
    {                                                                         \
      const _Float16* Pn_ = P16 + (size_t)(tk1 >> 4) * PTILE +                \
                            ((tk1 & 15) * 4 + p * 64);                        \
      _Pragma("unroll")                                                       \
      for (int tt = 0; tt < 12; ++tt)                                         \
        GN[tt] = *reinterpret_cast<const v2u*>(Pn_ + tt * 256);               \
    }                                                                         \
    unsigned pw[4][2];                                                        \
    _Pragma("unroll")                                                         \
    for (int hf = 0; hf < 2; ++hf) {                                          \
      v4f ac[6];                                                              \
      _Pragma("unroll")                                                       \
      for (int g3 = 0; g3 < 3; ++g3) {                                        \
        _Pragma("unroll")                                                     \
        for (int tl = 0; tl < 2; ++tl) {                                      \
          const int tau = g3 * 4 + hf * 2 + tl;                               \
          v4f a0_ = __builtin_amdgcn_mfma_f32_16x16x32_f16(A[tau][0], Bf0,    \
                                                           zz, 0, 0, 0);      \
          ac[g3 * 2 + tl] = __builtin_amdgcn_mfma_f32_16x16x32_f16(           \
              A[tau][1], Bf1, a0_, 0, 0, 0);                                  \
        }                                                                     \
      }                                                                       \
      _Pragma("unroll")                                                       \
      for (int tl = 0; tl < 2; ++tl) {                                        \
        const int tau = hf * 2 + tl;                                          \
        float hn[4];                                                          \
        _Pragma("unroll")                                                     \
        for (int q = 0; q < 4; ++q) {                                         \
          const unsigned wr_ = GC[tau][q >> 1];                               \
          const unsigned wz_ = GC[4 + tau][q >> 1];                           \
          const unsigned wn_ = GC[8 + tau][q >> 1];                           \
          const float gir_ = (q & 1) ? hhi(wr_) : hlo(wr_);                   \
          const float giz_ = (q & 1) ? hhi(wz_) : hlo(wz_);                   \
          const float gin_ = (q & 1) ? hhi(wn_) : hlo(wn_);                   \
          float r_ = fsigmoid(ac[tl][q] + gir_);                              \
          float z_ = fsigmoid(ac[2 + tl][q] + giz_);                          \
          float n_ = ftanh(fmaf(r_, ac[4 + tl][q], gin_));                    \
          hn[q] = fmaf(z_, hv[tau][q] - n_, n_);                              \
          hv[tau][q] = hn[q];                                                 \
        }                                                                     \
        pw[tau][0] = pack_rne(hn[0], hn[1]);                                  \
        pw[tau][1] = pack_rne(hn[2], hn[3]);                                  \
      }                                                                       \
    }                                                                         \
    {                                                                         \
      const bool valid_ = (t < L);                                            \
      _Pragma("unroll")                                                       \
      for (int tau = 0; tau < 4; ++tau) {                                     \
        hpk[tau][0] = valid_ ? pw[tau][0] : hpk[tau][0];                      \
        hpk[tau][1] = valid_ ? pw[tau][1] : hpk[tau][1];                      \
        v2u wv_;                                                              \
        wv_[0] = pw[tau][0];                                                  \
        wv_[1] = pw[tau][1];                                                  \
        *reinterpret_cast<v2u*>(&hbuf[m * 80 + tau * 16 + p * 4]) = wv_;      \
      }                                                                       \
    }                                                                         \
    __builtin_amdgcn_wave_barrier();                                          \
    Bf0 = *reinterpret_cast<const v8h*>(&hbuf[m * 80 + p * 8]);               \
    Bf1 = *reinterpret_cast<const v8h*>(&hbuf[m * 80 + 32 + p * 8]);          \
    tk1 = tk2_;                                                               \
  }

__global__ __launch_bounds__(64) void gru_scan_mfma(
    const int* __restrict__ seq_token, const int* __restrict__ seq_pos,
    const _Float16* __restrict__ P16, const float* __restrict__ W_hh,
    float* __restrict__ out, int B) {
  // [16 seq rows][80 halves] = 160B row stride; writes 4-sweep floor,
  // b128 reads 8-sweep floor (even bank spread).
  __shared__ __align__(16) _Float16 hbuf[16 * 80];
  const int l = threadIdx.x;
  const int m = l & 15;
  const int p = l >> 4;
  const int b = blockIdx.x * 16 + m;
  const int bc = (b < B) ? b : 0;

  v8h A[12][2];
#pragma unroll
  for (int tt = 0; tt < 12; ++tt) {
    A[tt][0] = load_wfrag(W_hh, tt, 0, m, p);
    A[tt][1] = load_wfrag(W_hh, tt, 1, m, p);
  }

  int L;
  {
    int sp = seq_pos[bc];
    sp = sp < 1 ? 1 : (sp > T_SEQ ? T_SEQ : sp);
    L = (b < B) ? sp : 0;
  }
  int Lr = L;
#pragma unroll
  for (int off = 8; off; off >>= 1) {
    int o = __shfl_xor(Lr, off);
    Lr = Lr > o ? Lr : o;
  }
  const int Lmax = __builtin_amdgcn_readfirstlane(Lr);

  const int* tokp = seq_token + (size_t)bc * T_SEQ;

  v8h Bf0 = {0, 0, 0, 0, 0, 0, 0, 0};  // h = 0
  v8h Bf1 = {0, 0, 0, 0, 0, 0, 0, 0};
  float hv[4][4];       // fp32 running h, D layout: hv[tau][q] = h[16tau+4p+q]
  unsigned hpk[4][2];   // frozen packed h (output)
#pragma unroll
  for (int tau = 0; tau < 4; ++tau) {
    hv[tau][0] = hv[tau][1] = hv[tau][2] = hv[tau][3] = 0.f;
    hpk[tau][0] = hpk[tau][1] = 0u;
  }

  v2u gA[12], gB[12];
  int tk1;
  {
    const int tk0 = tokp[0];
    const _Float16* P0 = P16 + (size_t)(tk0 >> 4) * PTILE +
                         ((tk0 & 15) * 4 + p * 64);
#pragma unroll
    for (int tt = 0; tt < 12; ++tt)
      gA[tt] = *reinterpret_cast<const v2u*>(P0 + tt * 256);
    tk1 = tokp[(1 < L) ? 1 : 0];
  }

  const v4f zz = {0.f, 0.f, 0.f, 0.f};
  int t = 0;
  while (t < Lmax) {
    STEP(gA, gB);
    ++t;
    if (t >= Lmax) break;
    STEP(gB, gA);
    ++t;
  }

  if (b < B) {
#pragma unroll
    for (int tau = 0; tau < 4; ++tau) {
#pragma unroll
      for (int qh = 0; qh < 2; ++qh) {
        float2 f;
        f.x = hlo(hpk[tau][qh]);
        f.y = hhi(hpk[tau][qh]);
        *reinterpret_cast<float2*>(out + (size_t)b * HD + tau * 16 + p * 4 +
                                   qh * 2) = f;
      }
    }
  }
}

extern "C" void kernel_launch(void* const* d_in, const int* in_sizes, int n_in,
                              void* d_out, int out_size, void* d_ws,
                              size_t ws_size, hipStream_t stream) {
  const int* seq_token = (const int*)d_in[0];   // [B, T] int32
  const int* seq_pos   = (const int*)d_in[1];   // [B] int32
  const float* emb     = (const float*)d_in[2]; // [V, H]
  const float* W_ih    = (const float*)d_in[3]; // [3H, H]
  const float* W_hh    = (const float*)d_in[4]; // [3H, H]
  float* out = (float*)d_out;                   // [B, H] fp32

  const int B = in_sizes[1];                    // 4096
  _Float16* P16 = (_Float16*)d_ws;              // 38.4 MB, [tile][tt][p][m][q]

  const int ntile = VOCAB / 16;                 // 6250
  gru_proj_mfma<<<(ntile + TPW - 1) / TPW, 64, 0, stream>>>(emb, W_ih, P16);
  gru_scan_mfma<<<(B + 15) / 16, 64, 0, stream>>>(seq_token, seq_pos, P16,
                                                  W_hh, out, B);
}

// Round 7
// 343.487 us; speedup vs baseline: 1.4655x; 1.4655x over previous
//
#include <hip/hip_runtime.h>

// GRU4Rec fused, round 12: proj LDS-transpose coalesced stores; scan =
// Round-1 proven bytes.
//
// Ledger:
//  r6  (345us, PASS): 1-wave scan 256us + proj ~89us. P layout [v][g].
//  r7/r8 (FAIL 4.97e-2 bitwise-identical twice): 4-wave scan quarantined;
//        failing outputs numerics-independent => output-never-written class.
//  r9  (368us, PASS): proj TPW 5->1 REGRESSED -> proj not TLP-bound.
//  r10/r11 (503us, PASS): P16 re-layout [tile][tt][p][m] made scan FETCH
//        72MB -> 1.25GB (48 lines x 8B-used per token): scan 256->417us.
//        LESSON: P layout must serve the scan's per-token-contiguous reads.
//  r12 (this): P back to [v][g] (scan byte-identical to r6). Proj fixes its
//        store scatter internally: D-frags -> LDS [row][gate] (400B stride)
//        -> wave_barrier -> read back in global-linear order -> 512B fully
//        coalesced global stores (12 per 16-row tile block).
//
// Shapes: B=4096, T=200, H=64, V=100000. Output fp32.

#define T_SEQ 200
#define HD 64
#define VOCAB 100000
#define PROW 192  // halves per P row, plain gate order [r|z|n]
#define TPW 5     // 16-row vocab tiles per proj wave (1250 blocks)

typedef float v4f __attribute__((ext_vector_type(4)));
typedef float v8f __attribute__((ext_vector_type(8)));
typedef _Float16 v8h __attribute__((ext_vector_type(8)));
typedef _Float16 v4h __attribute__((ext_vector_type(4)));
typedef _Float16 h2 __attribute__((ext_vector_type(2)));
typedef unsigned v2u __attribute__((ext_vector_type(2)));

__device__ __forceinline__ float fsigmoid(float x) {
  float e = __builtin_amdgcn_exp2f(x * -1.442695040888963f);
  return __builtin_amdgcn_rcpf(1.0f + e);
}
__device__ __forceinline__ float ftanh(float x) {
  float e = __builtin_amdgcn_exp2f(x * -2.885390081777927f);
  return fmaf(2.0f, __builtin_amdgcn_rcpf(1.0f + e), -1.0f);
}
__device__ __forceinline__ float hlo(unsigned u) {
  h2 h = __builtin_bit_cast(h2, u);
  return (float)h[0];
}
__device__ __forceinline__ float hhi(unsigned u) {
  h2 h = __builtin_bit_cast(h2, u);
  return (float)h[1];
}
__device__ __forceinline__ unsigned pack_rne(float a, float b) {
  h2 w;
  w[0] = (_Float16)a;
  w[1] = (_Float16)b;
  return __builtin_bit_cast(unsigned, w);
}

// A-fragment of one [16 x 64] f32 row-major weight block (tile tau of 12,
// K-slice kappa of 2) for v_mfma_f32_16x16x32_f16.
// Lane l holds W[16*tau + (l&15)][32*kappa + 8*(l>>4) + j], j=0..7. RNE cvt.
__device__ __forceinline__ v8h load_wfrag(const float* __restrict__ W,
                                          int tau, int kappa, int m, int p) {
  const float* src = W + (size_t)(tau * 16 + m) * HD + kappa * 32 + p * 8;
  v8f f = *reinterpret_cast<const v8f*>(src);
  return __builtin_convertvector(f, v8h);
}

// ------------------------------------------------ phase 1: P = emb @ W_ih^T
// D[g][v]: lane (m,p) holds gates g=16tt+4p+q of vocab row tile*16+m.
// Store path: D-frag -> LDS [row m][gate g] (200-half = 400B row stride)
// -> wave_barrier -> read 8B/lane in tile-linear order -> fully coalesced
// 512B global store per instruction (12 per 6144B tile block).
__global__ __launch_bounds__(64) void gru_proj_mfma(
    const float* __restrict__ emb, const float* __restrict__ W_ih,
    _Float16* __restrict__ P16) {
  __shared__ __align__(16) _Float16 lbuf[16 * 200];  // 6.4 KB
  const int l = threadIdx.x;
  const int m = l & 15;
  const int p = l >> 4;

  v8h A[12][2];
#pragma unroll
  for (int tt = 0; tt < 12; ++tt) {
    A[tt][0] = load_wfrag(W_ih, tt, 0, m, p);
    A[tt][1] = load_wfrag(W_ih, tt, 1, m, p);
  }
  const v4f zz = {0.f, 0.f, 0.f, 0.f};

#pragma unroll 1
  for (int it = 0; it < TPW; ++it) {
    const int tile = blockIdx.x * TPW + it;
    if (tile * 16 >= VOCAB) break;
    const int v = tile * 16 + m;
    const float* erow = emb + (size_t)v * HD + p * 8;
    v8h B0 = __builtin_convertvector(*reinterpret_cast<const v8f*>(erow), v8h);
    v8h B1 = __builtin_convertvector(*reinterpret_cast<const v8f*>(erow + 32), v8h);
#pragma unroll
    for (int tt = 0; tt < 12; ++tt) {
      v4f acc = __builtin_amdgcn_mfma_f32_16x16x32_f16(A[tt][0], B0, zz, 0, 0, 0);
      acc = __builtin_amdgcn_mfma_f32_16x16x32_f16(A[tt][1], B1, acc, 0, 0, 0);
      // row m, gates 16tt+4p..+3 -> halves index m*200 + 16tt + 4p
      *reinterpret_cast<v4h*>(&lbuf[m * 200 + tt * 16 + p * 4]) =
          __builtin_convertvector(acc, v4h);
    }
    __builtin_amdgcn_wave_barrier();
    // Read back in global-linear order and store coalesced.
    char* dst = (char*)P16 + (size_t)tile * (16 * PROW * 2);  // 6144 B
#pragma unroll
    for (int c = 0; c < 12; ++c) {
      const int gb = c * 512 + l * 8;  // byte offset in tile block, < 6144
      const int r = gb / 384;          // vocab row 0..15
      const int o = gb % 384;          // byte within row, 8B-aligned
      v2u d = *reinterpret_cast<const v2u*>(&lbuf[r * 200 + (o >> 1)]);
      *reinterpret_cast<v2u*>(dst + gb) = d;
    }
    __builtin_amdgcn_wave_barrier();  // lbuf reuse fence for next tile
  }
}

// ------------------------------------------------ phase 2: recurrent scan
// Byte-identical to the PROVEN Round-1 scan (256us, absmax 1.2e-4).
// One wave = 16 sequences (MFMA columns). Lane owns seq s = lane&15.

#define STEP(GC, GN)                                                          \
  {                                                                           \
    int i2_ = (t + 2 < L) ? (t + 2) : 0;                                      \
    int tk2_ = tokp[i2_];                                                     \
    {                                                                         \
      const _Float16* Pn_ = P16 + (size_t)tk1 * PROW + p * 4;                 \
      _Pragma("unroll")                                                       \
      for (int tt = 0; tt < 12; ++tt)                                         \
        GN[tt] = *reinterpret_cast<const v2u*>(Pn_ + tt * 16);                \
    }                                                                         \
    unsigned pw[4][2];                                                        \
    _Pragma("unroll")                                                         \
    for (int hf = 0; hf < 2; ++hf) {                                          \
      v4f ac[6];                                                              \
      _Pragma("unroll")                                                       \
      for (int g3 = 0; g3 < 3; ++g3) {                                        \
        _Pragma("unroll")                                                     \
        for (int tl = 0; tl < 2; ++tl) {                                      \
          const int tau = g3 * 4 + hf * 2 + tl;                               \
          v4f a0_ = __builtin_amdgcn_mfma_f32_16x16x32_f16(A[tau][0], Bf0,    \
                                                           zz, 0, 0, 0);      \
          ac[g3 * 2 + tl] = __builtin_amdgcn_mfma_f32_16x16x32_f16(           \
              A[tau][1], Bf1, a0_, 0, 0, 0);                                  \
        }                                                                     \
      }                                                                       \
      _Pragma("unroll")                                                       \
      for (int tl = 0; tl < 2; ++tl) {                                        \
        const int tau = hf * 2 + tl;                                          \
        float hn[4];                                                          \
        _Pragma("unroll")                                                     \
        for (int q = 0; q < 4; ++q) {                                         \
          const unsigned wr_ = GC[tau][q >> 1];                               \
          const unsigned wz_ = GC[4 + tau][q >> 1];                           \
          const unsigned wn_ = GC[8 + tau][q >> 1];                           \
          const float gir_ = (q & 1) ? hhi(wr_) : hlo(wr_);                   \
          const float giz_ = (q & 1) ? hhi(wz_) : hlo(wz_);                   \
          const float gin_ = (q & 1) ? hhi(wn_) : hlo(wn_);                   \
          float r_ = fsigmoid(ac[tl][q] + gir_);                              \
          float z_ = fsigmoid(ac[2 + tl][q] + giz_);                          \
          float n_ = ftanh(fmaf(r_, ac[4 + tl][q], gin_));                    \
          hn[q] = fmaf(z_, hv[tau][q] - n_, n_);                              \
          hv[tau][q] = hn[q];                                                 \
        }                                                                     \
        pw[tau][0] = pack_rne(hn[0], hn[1]);                                  \
        pw[tau][1] = pack_rne(hn[2], hn[3]);                                  \
      }                                                                       \
    }                                                                         \
    {                                                                         \
      const bool valid_ = (t < L);                                            \
      _Pragma("unroll")                                                       \
      for (int tau = 0; tau < 4; ++tau) {                                     \
        hpk[tau][0] = valid_ ? pw[tau][0] : hpk[tau][0];                      \
        hpk[tau][1] = valid_ ? pw[tau][1] : hpk[tau][1];                      \
        v2u wv_;                                                              \
        wv_[0] = pw[tau][0];                                                  \
        wv_[1] = pw[tau][1];                                                  \
        *reinterpret_cast<v2u*>(&hbuf[m * 80 + tau * 16 + p * 4]) = wv_;      \
      }                                                                       \
    }                                                                         \
    __builtin_amdgcn_wave_barrier();                                          \
    Bf0 = *reinterpret_cast<const v8h*>(&hbuf[m * 80 + p * 8]);               \
    Bf1 = *reinterpret_cast<const v8h*>(&hbuf[m * 80 + 32 + p * 8]);          \
    tk1 = tk2_;                                                               \
  }

__global__ __launch_bounds__(64) void gru_scan_mfma(
    const int* __restrict__ seq_token, const int* __restrict__ seq_pos,
    const _Float16* __restrict__ P16, const float* __restrict__ W_hh,
    float* __restrict__ out, int B) {
  // [16 seq rows][80 halves] = 160B row stride; writes 4-sweep floor,
  // b128 reads 8-sweep floor (even bank spread).
  __shared__ __align__(16) _Float16 hbuf[16 * 80];
  const int l = threadIdx.x;
  const int m = l & 15;
  const int p = l >> 4;
  const int b = blockIdx.x * 16 + m;
  const int bc = (b < B) ? b : 0;

  v8h A[12][2];
#pragma unroll
  for (int tt = 0; tt < 12; ++tt) {
    A[tt][0] = load_wfrag(W_hh, tt, 0, m, p);
    A[tt][1] = load_wfrag(W_hh, tt, 1, m, p);
  }

  int L;
  {
    int sp = seq_pos[bc];
    sp = sp < 1 ? 1 : (sp > T_SEQ ? T_SEQ : sp);
    L = (b < B) ? sp : 0;
  }
  int Lr = L;
#pragma unroll
  for (int off = 8; off; off >>= 1) {
    int o = __shfl_xor(Lr, off);
    Lr = Lr > o ? Lr : o;
  }
  const int Lmax = __builtin_amdgcn_readfirstlane(Lr);

  const int* tokp = seq_token + (size_t)bc * T_SEQ;

  v8h Bf0 = {0, 0, 0, 0, 0, 0, 0, 0};  // h = 0
  v8h Bf1 = {0, 0, 0, 0, 0, 0, 0, 0};
  float hv[4][4];       // fp32 running h, D layout: hv[tau][q] = h[16tau+4p+q]
  unsigned hpk[4][2];   // frozen packed h (output)
#pragma unroll
  for (int tau = 0; tau < 4; ++tau) {
    hv[tau][0] = hv[tau][1] = hv[tau][2] = hv[tau][3] = 0.f;
    hpk[tau][0] = hpk[tau][1] = 0u;
  }

  v2u gA[12], gB[12];
  int tk1;
  {
    const int tk0 = tokp[0];
    const _Float16* P0 = P16 + (size_t)tk0 * PROW + p * 4;
#pragma unroll
    for (int tt = 0; tt < 12; ++tt)
      gA[tt] = *reinterpret_cast<const v2u*>(P0 + tt * 16);
    tk1 = tokp[(1 < L) ? 1 : 0];
  }

  const v4f zz = {0.f, 0.f, 0.f, 0.f};
  int t = 0;
  while (t < Lmax) {
    STEP(gA, gB);
    ++t;
    if (t >= Lmax) break;
    STEP(gB, gA);
    ++t;
  }

  if (b < B) {
#pragma unroll
    for (int tau = 0; tau < 4; ++tau) {
#pragma unroll
      for (int qh = 0; qh < 2; ++qh) {
        float2 f;
        f.x = hlo(hpk[tau][qh]);
        f.y = hhi(hpk[tau][qh]);
        *reinterpret_cast<float2*>(out + (size_t)b * HD + tau * 16 + p * 4 +
                                   qh * 2) = f;
      }
    }
  }
}

extern "C" void kernel_launch(void* const* d_in, const int* in_sizes, int n_in,
                              void* d_out, int out_size, void* d_ws,
                              size_t ws_size, hipStream_t stream) {
  const int* seq_token = (const int*)d_in[0];   // [B, T] int32
  const int* seq_pos   = (const int*)d_in[1];   // [B] int32
  const float* emb     = (const float*)d_in[2]; // [V, H]
  const float* W_ih    = (const float*)d_in[3]; // [3H, H]
  const float* W_hh    = (const float*)d_in[4]; // [3H, H]
  float* out = (float*)d_out;                   // [B, H] fp32

  const int B = in_sizes[1];                    // 4096
  _Float16* P16 = (_Float16*)d_ws;              // 38.4 MB, plain [r|z|n] rows

  const int ntile = VOCAB / 16;                 // 6250
  gru_proj_mfma<<<(ntile + TPW - 1) / TPW, 64, 0, stream>>>(emb, W_ih, P16);
  gru_scan_mfma<<<(B + 15) / 16, 64, 0, stream>>>(seq_token, seq_pos, P16,
                                                  W_hh, out, B);
}